// Round 1
// 1381.890 us; speedup vs baseline: 1.2088x; 1.2088x over previous
//
#include <hip/hip_runtime.h>
#include <hip/hip_bf16.h>

// Problem constants (match reference setup_inputs)
#define Bb 64
#define Tt 256
#define Ee 300
#define Hh 512
#define NSTEP (2 * Tt - 1)  // 511
#define NNODE (Tt - 1)      // 255
#define N5H (5 * Hh)        // 2560

// Group decomposition: 8 groups x 32 blocks; each group owns 8 batches
// end-to-end and (in fast mode) lives on ONE XCD so node h/c handoff goes
// through the XCD-local L2. Block = member 'mem' owns 16 j-cols; its W_r
// slice (80 gate-cols x K=1024, bf16) is resident in VGPRs (no LDS W).
#define NG 8
#define GBATCH 8
#define NBLK 32
#define JPB 16
#define NC 80   // JPB * 5 gate-cols per block
// sync area: [0]=grid arrival, [1]=mode (0 unset / 1 LLC / 2 XCD-local),
// [2..9]=per-XCD census counts, [16 + g*1024 + lev*4] = per-group per-level
// arrival counters (16B strided to limit line sharing).
#define SYNC_INTS (16 + NG * 1024)

typedef __bf16 v8bf __attribute__((ext_vector_type(8)));
typedef float v4f __attribute__((ext_vector_type(4)));
typedef unsigned long long u64;
typedef unsigned int u32;
typedef unsigned char u8;

__device__ __forceinline__ float sigm(float x) { return 1.f / (1.f + __expf(-x)); }

// ---------------------------------------------------------------------------
// Phase 1: leaf buffer projections (unchanged, proven).
// ---------------------------------------------------------------------------
__global__ __launch_bounds__(256) void leaf_kernel(
    const float* __restrict__ x, const float* __restrict__ Wx,
    const float* __restrict__ bx, const float* __restrict__ Wg,
    const float* __restrict__ bg,
    __hip_bfloat16* __restrict__ leaf_h, float* __restrict__ leaf_c)
{
    __shared__ __align__(16) float xs[16][304];
    const int tid = threadIdx.x;
    const int n = blockIdx.x * 256 + tid;
    const long r0 = (long)blockIdx.y * 16;

    for (int i = tid; i < 16 * Ee; i += 256) {
        int r = i / Ee, k = i - r * Ee;
        xs[r][k] = x[(r0 + r) * Ee + k];
    }
    __syncthreads();

    float accx[16], accg[16];
    const float bxv = bx[n], bgv = bg[n];
#pragma unroll
    for (int r = 0; r < 16; r++) { accx[r] = bxv; accg[r] = bgv; }

    for (int k = 0; k < Ee; k += 4) {
        float wx[4], wg[4];
#pragma unroll
        for (int u = 0; u < 4; u++) {
            wx[u] = Wx[(long)(k + u) * Hh + n];
            wg[u] = Wg[(long)(k + u) * Hh + n];
        }
#pragma unroll
        for (int r = 0; r < 16; r++) {
            const float4 xv = *(const float4*)&xs[r][k];
            accx[r] = fmaf(xv.x, wx[0], accx[r]);
            accx[r] = fmaf(xv.y, wx[1], accx[r]);
            accx[r] = fmaf(xv.z, wx[2], accx[r]);
            accx[r] = fmaf(xv.w, wx[3], accx[r]);
            accg[r] = fmaf(xv.x, wg[0], accg[r]);
            accg[r] = fmaf(xv.y, wg[1], accg[r]);
            accg[r] = fmaf(xv.z, wg[2], accg[r]);
            accg[r] = fmaf(xv.w, wg[3], accg[r]);
        }
    }
#pragma unroll
    for (int r = 0; r < 16; r++) {
        const float c = accx[r];
        const float h = sigm(accg[r]) * tanhf(c);
        const long idx = (r0 + r) * Hh + n;
        leaf_c[idx] = c;
        leaf_h[idx] = __float2bfloat16(h);
    }
}

// ---------------------------------------------------------------------------
// Phase 1b: pre-transpose W_r -> WtG[gc][k] bf16 (coalesced both sides).
// Same float->__bf16 conversion path as the previous in-kernel staging.
// ---------------------------------------------------------------------------
__global__ __launch_bounds__(256) void wtr_kernel(const float* __restrict__ Wr,
                                                  __hip_bfloat16* __restrict__ WtG)
{
    __shared__ float ts[64][65];
    const int tid = threadIdx.x;
    const long g0 = (long)blockIdx.x * 64;  // gate-col tile (2560/64 = 40)
    const int k0 = (int)blockIdx.y * 64;    // k tile       (1024/64 = 16)
    const int r = tid >> 6;                 // 0..3
    const int c = tid & 63;
    __bf16* Wo = (__bf16*)WtG;
#pragma unroll
    for (int i = 0; i < 16; i++)
        ts[r + i * 4][c] = Wr[(long)(k0 + r + i * 4) * N5H + g0 + c];
    __syncthreads();
#pragma unroll
    for (int i = 0; i < 16; i++)
        Wo[(g0 + r + i * 4) * 1024 + k0 + c] = (__bf16)ts[c][r + i * 4];
}

// ---------------------------------------------------------------------------
// Phase 2: schedule. Per-GROUP (8 batches) level buckets. Zeros the sync area.
// ---------------------------------------------------------------------------
__global__ __launch_bounds__(64) void sched_kernel(
    const int* __restrict__ trans,
    int* __restrict__ node_l, int* __restrict__ node_r,
    int* __restrict__ root_src, int* __restrict__ offs,   // [NG*257]
    int* __restrict__ items, int* __restrict__ max_lv,    // [NG*GBATCH*NNODE], [NG]
    int* __restrict__ sync)                               // SYNC_INTS ints
{
    __shared__ short stck[Bb][Tt];
    __shared__ unsigned char lvl[Bb][NNODE];
    __shared__ unsigned char trans_s[NSTEP][Bb];
    __shared__ int counts[NG][256];
    __shared__ int offs_s[NG][257];
    __shared__ int maxl_s[NG];
    const int b = threadIdx.x;

    if (b < NG) maxl_s[b] = 0;
    for (int i4 = b; i4 < SYNC_INTS / 4; i4 += Bb)
        ((int4*)sync)[i4] = make_int4(0, 0, 0, 0);
    for (int i = b; i < NG * 256; i += Bb) counts[i >> 8][i & 255] = 0;
    for (int i4 = b; i4 < (NSTEP * Bb) / 4; i4 += Bb) {
        const int4 v = ((const int4*)trans)[i4];
        const int f = 4 * i4;
        trans_s[(f + 0) >> 6][(f + 0) & 63] = (unsigned char)v.x;
        trans_s[(f + 1) >> 6][(f + 1) & 63] = (unsigned char)v.y;
        trans_s[(f + 2) >> 6][(f + 2) & 63] = (unsigned char)v.z;
        trans_s[(f + 3) >> 6][(f + 3) & 63] = (unsigned char)v.w;
    }
    __syncthreads();

    int sp = 0, bp = Tt, nid = 0, maxl = 0;
    for (int t = 0; t < NSTEP; t++) {
        if (trans_s[t][b] == 0) {
            bp -= 1;
            stck[b][sp] = (short)bp; sp += 1;
        } else {
            const int rs = stck[b][sp - 1];
            const int ls = stck[b][sp - 2];
            const int l_lv = (ls < Tt) ? 0 : (int)lvl[b][ls - Tt];
            const int r_lv = (rs < Tt) ? 0 : (int)lvl[b][rs - Tt];
            const int le = 1 + (l_lv > r_lv ? l_lv : r_lv);
            lvl[b][nid] = (unsigned char)le;
            node_l[b * NNODE + nid] = (l_lv << 9) | ls;
            node_r[b * NNODE + nid] = (r_lv << 9) | rs;
            if (le > maxl) maxl = le;
            sp -= 2;
            stck[b][sp] = (short)(Tt + nid); sp += 1;
            nid += 1;
        }
    }
    root_src[b] = (int)stck[b][0];
    const int g = b >> 3;  // group of this batch (8 batches/group)
    for (int i = 0; i < nid; i++) atomicAdd(&counts[g][lvl[b][i]], 1);
    atomicMax(&maxl_s[g], maxl);
    __syncthreads();
    if (b < NG) {
        int acc = 0;
        for (int l = 0; l < 256; l++) { offs_s[b][l] = acc; acc += counts[b][l]; }
        offs_s[b][256] = acc;
        max_lv[b] = maxl_s[b];
    }
    __syncthreads();
    for (int i = b; i < NG * 256; i += Bb) counts[i >> 8][i & 255] = offs_s[i >> 8][i & 255];
    __syncthreads();
    for (int i = 0; i < nid; i++) {
        const int pos = atomicAdd(&counts[g][lvl[b][i]], 1);
        items[g * (GBATCH * NNODE) + pos] = (b << 16) | i;
    }
    for (int i = b; i < NG * 257; i += Bb) offs[i] = offs_s[i / 257][i % 257];
}

// ---------------------------------------------------------------------------
// Phase 3: 8 groups x 32 blocks. W_r slice in VGPRs (wreg[5][4] v8bf / lane).
// Runtime census via HW_REG_XCC_ID: if every XCD hosts exactly 32 blocks,
// group = XCD and node h/c use PLAIN cached stores (write-through L1 -> the
// group's shared L2) with s_waitcnt store-ack; otherwise fall back to the
// proven agent-scope (sc1 -> LLC) stores. Flags/arrival are device-scope
// LLC atomics in BOTH modes (one atomicAdd per block per level; pollers read
// a single counter). Readers always use plain cached loads: each node line
// is written once pre-arrival and read only post-poll, never re-read.
// ---------------------------------------------------------------------------
__global__ __launch_bounds__(512) void tree_kernel(
    const __hip_bfloat16* __restrict__ WtG, const float* __restrict__ br,
    const __hip_bfloat16* __restrict__ leaf_h, const float* __restrict__ leaf_c,
    __hip_bfloat16* __restrict__ node_h, float* __restrict__ node_c,
    const int* __restrict__ node_l, const int* __restrict__ node_r,
    const int* __restrict__ root_src, const int* __restrict__ offs,
    const int* __restrict__ items, const int* __restrict__ max_lv,
    float* __restrict__ out, int* __restrict__ sync)
{
    __shared__ float Cs[8][8][84];    // per-kq MFMA partials (rows 0..7 real)
    __shared__ float Cred[8][84];     // reduced gates + bias
    __shared__ float brs[NC];
    __shared__ u64 hPl[16], hPr[16], cPl[16], cPr[16];
    __shared__ int outm[16];          // item | flags (27:hotL 28:hotR 29:pad 30:root)
    __shared__ int s_info;
    __shared__ int force_pad[16384];  // 64 KB: forces 1 block/CU -> 32 blocks/XCD

    const int tid = threadIdx.x;

    // ---- census: discover XCD, claim rank, decide protocol mode ----
    if (tid == 0) {
        int xcc;
        asm volatile("s_getreg_b32 %0, hwreg(HW_REG_XCC_ID)" : "=s"(xcc));
        xcc &= 7;
        const int rank = atomicAdd(&sync[2 + xcc], 1);
        __builtin_amdgcn_s_waitcnt(0);  // rank add acked before grid arrival
        const int n = atomicAdd(&sync[0], 1);
        if (n == 255) {
            int ok = 1;
            for (int i = 0; i < 8; i++)
                ok &= (__hip_atomic_load(&sync[2 + i], __ATOMIC_RELAXED,
                                         __HIP_MEMORY_SCOPE_AGENT) == NBLK);
            __hip_atomic_store(&sync[1], ok ? 2 : 1, __ATOMIC_RELAXED,
                               __HIP_MEMORY_SCOPE_AGENT);
        }
        int m;
        while ((m = __hip_atomic_load(&sync[1], __ATOMIC_RELAXED,
                                      __HIP_MEMORY_SCOPE_AGENT)) == 0) {}
        const int grp_ = (m == 2) ? xcc : ((int)blockIdx.x >> 5);
        const int mem_ = (m == 2) ? rank : ((int)blockIdx.x & 31);
        s_info = (m << 16) | (grp_ << 8) | mem_;
    }
    __syncthreads();
    const int info0 = s_info;
    const bool l2m = (info0 >> 16) == 2;
    const int grp = (info0 >> 8) & 255;
    const int mem = info0 & 255;
    const int j0 = mem * JPB;

    const int* offsG = offs + grp * 257;
    const int* itemsG = items + grp * (GBATCH * NNODE);
    int* cntG = sync + 16 + grp * 1024;

    const int ML = max_lv[grp];
    if (ML < 0) { volatile int* fp = force_pad; fp[tid] = 1; }  // keep pad live

    const int wave = tid >> 6;
    const int lane = tid & 63;
    const int quad = lane >> 4;
    const int l15 = lane & 15;
    const int kq = wave;  // K slice [kq*128, kq*128+128); kq<4 left child, else right

    u32* node_h32 = (u32*)node_h;

    // ---- W_r slice -> VGPRs: local col c=(gate, jl) maps to gcol=gate*H+j0+jl
    v8bf wreg[5][4];
#pragma unroll
    for (int nt = 0; nt < 5; nt++) {
        const int c = nt * 16 + l15;
        const long gcol = (long)((c % 5) * Hh + j0 + c / 5);
#pragma unroll
        for (int t = 0; t < 4; t++)
            wreg[nt][t] = *(const v8bf*)&WtG[gcol * 1024 + kq * 128 + t * 32 + quad * 8];
    }
    if (tid < NC) brs[tid] = br[(tid % 5) * Hh + j0 + tid / 5];

    // prep one chunk of up to 8 nodes (wave 0, lanes < 16; lanes >= M dup item 0).
    auto prep = [&](int base, int M, int plv) {
        if (lane < 16) {
            const int m = lane;
            const int it = itemsG[base + (m < M ? m : 0)];
            const int b = it >> 16;
            const int nd = it & 0xffff;
            const int lraw = node_l[b * NNODE + nd];
            const int rraw = node_r[b * NNODE + nd];
            const int ls = lraw & 511, llv = lraw >> 9;
            const int rs = rraw & 511, rlv = rraw >> 9;
            hPl[m] = (ls < Tt) ? (u64)(leaf_h + ((long)b * Tt + ls) * Hh)
                               : (u64)(node_h + ((long)b * NNODE + (ls - Tt)) * Hh);
            cPl[m] = (ls < Tt) ? (u64)(leaf_c + ((long)b * Tt + ls) * Hh)
                               : (u64)(node_c + ((long)b * NNODE + (ls - Tt)) * Hh);
            hPr[m] = (rs < Tt) ? (u64)(leaf_h + ((long)b * Tt + rs) * Hh)
                               : (u64)(node_h + ((long)b * NNODE + (rs - Tt)) * Hh);
            cPr[m] = (rs < Tt) ? (u64)(leaf_c + ((long)b * Tt + rs) * Hh)
                               : (u64)(node_c + ((long)b * NNODE + (rs - Tt)) * Hh);
            int fl = it;
            if (llv > 0 && llv == plv - 1) fl |= (1 << 27);  // hot left
            if (rlv > 0 && rlv == plv - 1) fl |= (1 << 28);  // hot right
            if (Tt + nd == root_src[b]) fl |= (1 << 30);
            if (m >= M) fl |= (1 << 29);
            outm[m] = fl;
        }
    };

    // Epilogue (wave 0): lane -> node m=lane>>3, local j pair jl2=(lane&7)*2.
    auto epilogue = [&](float clv0, float clv1, float crv0, float crv1) {
        const int m = lane >> 3;
        const int jl2 = (lane & 7) * 2;
        const int info = outm[m];
        if (!(info & (1 << 29))) {
            const int b = (info >> 16) & 63;
            const int nd = info & 0xffff;
            float cv[2], hv[2];
            const float clv[2] = {clv0, clv1};
            const float crv[2] = {crv0, crv1};
#pragma unroll
            for (int jj = 0; jj < 2; jj++) {
                const int jc = (jl2 + jj) * 5;
                const float iv = Cred[m][jc + 0];
                const float fl = Cred[m][jc + 1];
                const float fr = Cred[m][jc + 2];
                const float gv = Cred[m][jc + 3];
                const float ov = Cred[m][jc + 4];
                cv[jj] = sigm(iv) * tanhf(gv) + sigm(fl) * clv[jj] + sigm(fr) * crv[jj];
                hv[jj] = sigm(ov) * tanhf(cv[jj]);
            }
            union { float f[2]; u64 u; } cp;
            cp.f[0] = cv[0]; cp.f[1] = cv[1];
            const __hip_bfloat16 h0 = __float2bfloat16(hv[0]);
            const __hip_bfloat16 h1 = __float2bfloat16(hv[1]);
            const u32 hpack = (u32)(*(const unsigned short*)&h0)
                            | ((u32)(*(const unsigned short*)&h1) << 16);
            u64* cdst = (u64*)(node_c + ((long)b * NNODE + nd) * Hh + j0 + jl2);
            u32* hdst = node_h32 + ((long)b * NNODE + nd) * (Hh / 2) + (j0 + jl2) / 2;
            if (l2m) {
                *cdst = cp.u;   // plain: lands in this XCD's shared L2
                *hdst = hpack;
            } else {
                __hip_atomic_store(cdst, cp.u, __ATOMIC_RELAXED, __HIP_MEMORY_SCOPE_AGENT);
                __hip_atomic_store(hdst, hpack, __ATOMIC_RELAXED, __HIP_MEMORY_SCOPE_AGENT);
            }
            if (info & (1 << 30)) {
                out[(long)b * Hh + j0 + jl2]     = hv[0];
                out[(long)b * Hh + j0 + jl2 + 1] = hv[1];
            }
        }
    };

    // MFMA for current chunk from registers; B operands from wreg (VGPR).
    auto do_mfma = [&](v8bf a0, v8bf a1, v8bf a2, v8bf a3) {
        v8bf a[4] = {a0, a1, a2, a3};
#pragma unroll
        for (int nt = 0; nt < 5; nt++) {
            v4f acc = {0.f, 0.f, 0.f, 0.f};
#pragma unroll
            for (int t = 0; t < 4; t++)
                acc = __builtin_amdgcn_mfma_f32_16x16x32_bf16(a[t], wreg[nt][t], acc, 0, 0, 0);
            if (quad < 2) {
#pragma unroll
                for (int rg = 0; rg < 4; rg++)
                    Cs[kq][quad * 4 + rg][nt * 16 + l15] = acc[rg];
            }
        }
    };

    // Reduce Cs over kq + bias -> Cred (all 512 threads).
    auto reduce = [&]() {
        for (int t = tid; t < 8 * NC; t += 512) {
            const int m = t / NC, c = t - m * NC;
            float r = brs[c];
#pragma unroll
            for (int w = 0; w < 8; w++) r += Cs[w][m][c];
            Cred[m][c] = r;
        }
    };

    // Initial prep: level 1, chunk 0.
    if (wave == 0 && ML >= 1) {
        const int s1 = offsG[1], e1 = offsG[2];
        prep(s1, (e1 - s1 < 8) ? (e1 - s1) : 8, 1);
    }
    __syncthreads();

    for (int lev = 1; lev <= ML; lev++) {
        const int s = offsG[lev], e = offsG[lev + 1];

        // ---- Phase A (pre-poll): cold child gather for chunk 0 ----
        const int infoA = outm[l15];
        const bool hot = (infoA >> (27 + (kq >> 2))) & 1;
        const __hip_bfloat16* hp =
            (const __hip_bfloat16*)((kq < 4) ? hPl[l15] : hPr[l15]);
        const int kb = (kq & 3) * 128 + quad * 8;
        v8bf a0, a1, a2, a3;
        if (!hot) {
            a0 = *(const v8bf*)(hp + kb);
            a1 = *(const v8bf*)(hp + kb + 32);
            a2 = *(const v8bf*)(hp + kb + 64);
            a3 = *(const v8bf*)(hp + kb + 96);
        }
        float clv0 = 0.f, clv1 = 0.f, crv0 = 0.f, crv1 = 0.f;
        bool hotL = false, hotR = false;
        if (wave == 0) {
            const int ie = outm[lane >> 3];
            hotL = (ie >> 27) & 1;
            hotR = (ie >> 28) & 1;
            const int jo = j0 + (lane & 7) * 2;
            if (!hotL) {
                union { u64 u; float f[2]; } t;
                t.u = *(const u64*)((const float*)cPl[lane >> 3] + jo);
                clv0 = t.f[0]; clv1 = t.f[1];
            }
            if (!hotR) {
                union { u64 u; float f[2]; } t;
                t.u = *(const u64*)((const float*)cPr[lane >> 3] + jo);
                crv0 = t.f[0]; crv1 = t.f[1];
            }
        }

        // ---- Barrier: wave 0 polls this group's level counter (LLC) ----
        if (lev > 1 && wave == 0) {
            int* cw = cntG + (lev - 1) * 4;
            while (__hip_atomic_load(cw, __ATOMIC_RELAXED,
                                     __HIP_MEMORY_SCOPE_AGENT) < NBLK) {}
        }
        __syncthreads();

        // ---- Phase B (post-poll): hot gather + MFMA ----
        if (hot) {
            a0 = *(const v8bf*)(hp + kb);
            a1 = *(const v8bf*)(hp + kb + 32);
            a2 = *(const v8bf*)(hp + kb + 64);
            a3 = *(const v8bf*)(hp + kb + 96);
        }
        if (wave == 0) {
            const int jo = j0 + (lane & 7) * 2;
            if (hotL) {
                union { u64 u; float f[2]; } t;
                t.u = *(const u64*)((const float*)cPl[lane >> 3] + jo);
                clv0 = t.f[0]; clv1 = t.f[1];
            }
            if (hotR) {
                union { u64 u; float f[2]; } t;
                t.u = *(const u64*)((const float*)cPr[lane >> 3] + jo);
                crv0 = t.f[0]; crv1 = t.f[1];
            }
        }
        do_mfma(a0, a1, a2, a3);
        __syncthreads();
        reduce();
        __syncthreads();
        if (wave == 0) epilogue(clv0, clv1, crv0, crv1);

        // ---- Rare extra chunks (>8 items/level): generic path ----
        for (int base = s + 8; base < e; base += 8) {
            __syncthreads();
            if (wave == 0) prep(base, (e - base < 8) ? (e - base) : 8, lev);
            __syncthreads();
            const __hip_bfloat16* hp2 =
                (const __hip_bfloat16*)((kq < 4) ? hPl[l15] : hPr[l15]);
            float xl0 = 0.f, xl1 = 0.f, xr0 = 0.f, xr1 = 0.f;
            if (wave == 0) {
                const int jo = j0 + (lane & 7) * 2;
                union { u64 u; float f[2]; } t;
                t.u = *(const u64*)((const float*)cPl[lane >> 3] + jo);
                xl0 = t.f[0]; xl1 = t.f[1];
                t.u = *(const u64*)((const float*)cPr[lane >> 3] + jo);
                xr0 = t.f[0]; xr1 = t.f[1];
            }
            do_mfma(*(const v8bf*)(hp2 + kb), *(const v8bf*)(hp2 + kb + 32),
                    *(const v8bf*)(hp2 + kb + 64), *(const v8bf*)(hp2 + kb + 96));
            __syncthreads();
            reduce();
            __syncthreads();
            if (wave == 0) epilogue(xl0, xl1, xr0, xr1);
        }

        // ---- Arrival (stores acked first) + next-level prep (wave 0) ----
        if (wave == 0) {
            __builtin_amdgcn_s_waitcnt(0);  // drain wave-0 h/c stores (L2 or LLC ack)
            if (lev < ML) {
                if (lane == 0) atomicAdd(cntG + lev * 4, 1);
                const int ns = offsG[lev + 1], ne = offsG[lev + 2];
                prep(ns, (ne - ns < 8) ? (ne - ns) : 8, lev + 1);
            }
        }
        __syncthreads();
    }
}

// ---------------------------------------------------------------------------
extern "C" void kernel_launch(void* const* d_in, const int* in_sizes, int n_in,
                              void* d_out, int out_size, void* d_ws, size_t ws_size,
                              hipStream_t stream)
{
    const float* x   = (const float*)d_in[0];
    const int* trans = (const int*)d_in[1];
    const float* Wx  = (const float*)d_in[2];
    const float* bx  = (const float*)d_in[3];
    const float* Wg  = (const float*)d_in[4];
    const float* bg  = (const float*)d_in[5];
    const float* Wr  = (const float*)d_in[6];
    const float* br  = (const float*)d_in[7];
    float* out = (float*)d_out;

    char* p = (char*)d_ws;
    auto take = [&](size_t bytes) -> char* {
        char* r = p;
        p += (bytes + 255) & ~(size_t)255;
        return r;
    };
    __hip_bfloat16* leaf_h = (__hip_bfloat16*)take((size_t)Bb * Tt * Hh * 2);
    float* leaf_c          = (float*)take((size_t)Bb * Tt * Hh * 4);
    __hip_bfloat16* node_h = (__hip_bfloat16*)take((size_t)Bb * NNODE * Hh * 2);
    float* node_c          = (float*)take((size_t)Bb * NNODE * Hh * 4);
    int* node_l   = (int*)take((size_t)Bb * NNODE * 4);
    int* node_r   = (int*)take((size_t)Bb * NNODE * 4);
    int* root_src = (int*)take(Bb * 4);
    int* offs     = (int*)take((size_t)NG * 257 * 4);
    int* items    = (int*)take((size_t)NG * GBATCH * NNODE * 4);
    int* max_lv   = (int*)take(NG * 4);
    __hip_bfloat16* WtG = (__hip_bfloat16*)take((size_t)N5H * 1024 * 2);
    int* sync     = (int*)take((size_t)SYNC_INTS * 4);

    hipLaunchKernelGGL(leaf_kernel, dim3(Hh / 256, (Bb * Tt) / 16), dim3(256), 0, stream,
                       x, Wx, bx, Wg, bg, leaf_h, leaf_c);
    hipLaunchKernelGGL(wtr_kernel, dim3(N5H / 64, 1024 / 64), dim3(256), 0, stream,
                       Wr, WtG);
    hipLaunchKernelGGL(sched_kernel, dim3(1), dim3(64), 0, stream,
                       trans, node_l, node_r, root_src, offs, items, max_lv, sync);

    void* args[] = { (void*)&WtG, (void*)&br, (void*)&leaf_h, (void*)&leaf_c,
                     (void*)&node_h, (void*)&node_c, (void*)&node_l, (void*)&node_r,
                     (void*)&root_src, (void*)&offs, (void*)&items, (void*)&max_lv,
                     (void*)&out, (void*)&sync };
    hipLaunchCooperativeKernel((const void*)tree_kernel, dim3(256), dim3(512),
                               args, 0, stream);
}

// Round 4
// 1259.757 us; speedup vs baseline: 1.3260x; 1.0969x over previous
//
#include <hip/hip_runtime.h>
#include <hip/hip_bf16.h>

// Problem constants (match reference setup_inputs)
#define Bb 64
#define Tt 256
#define Ee 300
#define Hh 512
#define NSTEP (2 * Tt - 1)  // 511
#define NNODE (Tt - 1)      // 255
#define N5H (5 * Hh)        // 2560

// Group decomposition: 8 groups x 32 blocks; each group owns 8 batches
// end-to-end and (in fast mode) lives on ONE XCD so node h/c handoff goes
// through the XCD-local L2. Block = member 'mem' owns 16 j-cols; its W_r
// slice (80 gate-cols x K=1024, bf16) lives in VGPRs.
#define NG 8
#define GBATCH 8
#define NBLK 32
#define JPB 16
#define NC 80   // JPB * 5 gate-cols per block
// sync area: [0]=grid arrival, [1]=mode (0 unset / 1 LLC / 2 XCD-local),
// [2..9]=per-XCD census counts, [16 + g*1024 + lev*4] = per-group per-level
// arrival counters (16B strided to limit line sharing). ALL sync counters
// are agent-scope (LLC) in both modes — proven across bench re-runs (R1);
// only the bulk h/c data path switches to plain cached stores in mode 2.
#define SYNC_INTS (16 + NG * 1024)

typedef __bf16 v8bf __attribute__((ext_vector_type(8)));
typedef float v4f __attribute__((ext_vector_type(4)));
typedef unsigned long long u64;
typedef unsigned int u32;
typedef unsigned char u8;

__device__ __forceinline__ float sigm(float x) { return 1.f / (1.f + __expf(-x)); }

// ---------------------------------------------------------------------------
// Phase 1: leaf buffer projections (unchanged, proven).
// ---------------------------------------------------------------------------
__global__ __launch_bounds__(256) void leaf_kernel(
    const float* __restrict__ x, const float* __restrict__ Wx,
    const float* __restrict__ bx, const float* __restrict__ Wg,
    const float* __restrict__ bg,
    __hip_bfloat16* __restrict__ leaf_h, float* __restrict__ leaf_c)
{
    __shared__ __align__(16) float xs[16][304];
    const int tid = threadIdx.x;
    const int n = blockIdx.x * 256 + tid;
    const long r0 = (long)blockIdx.y * 16;

    for (int i = tid; i < 16 * Ee; i += 256) {
        int r = i / Ee, k = i - r * Ee;
        xs[r][k] = x[(r0 + r) * Ee + k];
    }
    __syncthreads();

    float accx[16], accg[16];
    const float bxv = bx[n], bgv = bg[n];
#pragma unroll
    for (int r = 0; r < 16; r++) { accx[r] = bxv; accg[r] = bgv; }

    for (int k = 0; k < Ee; k += 4) {
        float wx[4], wg[4];
#pragma unroll
        for (int u = 0; u < 4; u++) {
            wx[u] = Wx[(long)(k + u) * Hh + n];
            wg[u] = Wg[(long)(k + u) * Hh + n];
        }
#pragma unroll
        for (int r = 0; r < 16; r++) {
            const float4 xv = *(const float4*)&xs[r][k];
            accx[r] = fmaf(xv.x, wx[0], accx[r]);
            accx[r] = fmaf(xv.y, wx[1], accx[r]);
            accx[r] = fmaf(xv.z, wx[2], accx[r]);
            accx[r] = fmaf(xv.w, wx[3], accx[r]);
            accg[r] = fmaf(xv.x, wg[0], accg[r]);
            accg[r] = fmaf(xv.y, wg[1], accg[r]);
            accg[r] = fmaf(xv.z, wg[2], accg[r]);
            accg[r] = fmaf(xv.w, wg[3], accg[r]);
        }
    }
#pragma unroll
    for (int r = 0; r < 16; r++) {
        const float c = accx[r];
        const float h = sigm(accg[r]) * tanhf(c);
        const long idx = (r0 + r) * Hh + n;
        leaf_c[idx] = c;
        leaf_h[idx] = __float2bfloat16(h);
    }
}

// ---------------------------------------------------------------------------
// Phase 1b: pre-transpose W_r -> WtG[gc][k] bf16 (coalesced both sides).
// ---------------------------------------------------------------------------
__global__ __launch_bounds__(256) void wtr_kernel(const float* __restrict__ Wr,
                                                  __hip_bfloat16* __restrict__ WtG)
{
    __shared__ float ts[64][65];
    const int tid = threadIdx.x;
    const long g0 = (long)blockIdx.x * 64;  // gate-col tile (2560/64 = 40)
    const int k0 = (int)blockIdx.y * 64;    // k tile       (1024/64 = 16)
    const int r = tid >> 6;                 // 0..3
    const int c = tid & 63;
    __bf16* Wo = (__bf16*)WtG;
#pragma unroll
    for (int i = 0; i < 16; i++)
        ts[r + i * 4][c] = Wr[(long)(k0 + r + i * 4) * N5H + g0 + c];
    __syncthreads();
#pragma unroll
    for (int i = 0; i < 16; i++)
        Wo[(g0 + r + i * 4) * 1024 + k0 + c] = (__bf16)ts[c][r + i * 4];
}

// ---------------------------------------------------------------------------
// Phase 2: schedule. Per-GROUP (8 batches) level buckets. Zeros the sync area.
// ---------------------------------------------------------------------------
__global__ __launch_bounds__(64) void sched_kernel(
    const int* __restrict__ trans,
    int* __restrict__ node_l, int* __restrict__ node_r,
    int* __restrict__ root_src, int* __restrict__ offs,   // [NG*257]
    int* __restrict__ items, int* __restrict__ max_lv,    // [NG*GBATCH*NNODE], [NG]
    int* __restrict__ sync)                               // SYNC_INTS ints
{
    __shared__ short stck[Bb][Tt];
    __shared__ unsigned char lvl[Bb][NNODE];
    __shared__ unsigned char trans_s[NSTEP][Bb];
    __shared__ int counts[NG][256];
    __shared__ int offs_s[NG][257];
    __shared__ int maxl_s[NG];
    const int b = threadIdx.x;

    if (b < NG) maxl_s[b] = 0;
    for (int i4 = b; i4 < SYNC_INTS / 4; i4 += Bb)
        ((int4*)sync)[i4] = make_int4(0, 0, 0, 0);
    for (int i = b; i < NG * 256; i += Bb) counts[i >> 8][i & 255] = 0;
    for (int i4 = b; i4 < (NSTEP * Bb) / 4; i4 += Bb) {
        const int4 v = ((const int4*)trans)[i4];
        const int f = 4 * i4;
        trans_s[(f + 0) >> 6][(f + 0) & 63] = (unsigned char)v.x;
        trans_s[(f + 1) >> 6][(f + 1) & 63] = (unsigned char)v.y;
        trans_s[(f + 2) >> 6][(f + 2) & 63] = (unsigned char)v.z;
        trans_s[(f + 3) >> 6][(f + 3) & 63] = (unsigned char)v.w;
    }
    __syncthreads();

    int sp = 0, bp = Tt, nid = 0, maxl = 0;
    for (int t = 0; t < NSTEP; t++) {
        if (trans_s[t][b] == 0) {
            bp -= 1;
            stck[b][sp] = (short)bp; sp += 1;
        } else {
            const int rs = stck[b][sp - 1];
            const int ls = stck[b][sp - 2];
            const int l_lv = (ls < Tt) ? 0 : (int)lvl[b][ls - Tt];
            const int r_lv = (rs < Tt) ? 0 : (int)lvl[b][rs - Tt];
            const int le = 1 + (l_lv > r_lv ? l_lv : r_lv);
            lvl[b][nid] = (unsigned char)le;
            node_l[b * NNODE + nid] = (l_lv << 9) | ls;
            node_r[b * NNODE + nid] = (r_lv << 9) | rs;
            if (le > maxl) maxl = le;
            sp -= 2;
            stck[b][sp] = (short)(Tt + nid); sp += 1;
            nid += 1;
        }
    }
    root_src[b] = (int)stck[b][0];
    const int g = b >> 3;  // group of this batch (8 batches/group)
    for (int i = 0; i < nid; i++) atomicAdd(&counts[g][lvl[b][i]], 1);
    atomicMax(&maxl_s[g], maxl);
    __syncthreads();
    if (b < NG) {
        int acc = 0;
        for (int l = 0; l < 256; l++) { offs_s[b][l] = acc; acc += counts[b][l]; }
        offs_s[b][256] = acc;
        max_lv[b] = maxl_s[b];
    }
    __syncthreads();
    for (int i = b; i < NG * 256; i += Bb) counts[i >> 8][i & 255] = offs_s[i >> 8][i & 255];
    __syncthreads();
    for (int i = 0; i < nid; i++) {
        const int pos = atomicAdd(&counts[g][lvl[b][i]], 1);
        items[g * (GBATCH * NNODE) + pos] = (b << 16) | i;
    }
    for (int i = b; i < NG * 257; i += Bb) offs[i] = offs_s[i / 257][i % 257];
}

// ---------------------------------------------------------------------------
// Phase 3: 8 groups x 32 blocks. W_r in VGPRs. Census via HW_REG_XCC_ID:
// mode 2 (each XCD hosts exactly one 32-block group) -> node h/c plain cached
// stores (write-through -> XCD L2). Mode 1 fallback: agent-scope (LLC)
// stores. Level-barrier: agent-scope atomicAdd arrival + agent-scope relaxed
// load poll (R1-proven protocol, kept in BOTH modes). NEW vs R1: the static
// schedule is precomputed ONCE into a 40 KB LDS metadata cache, removing the
// per-level wave-0 prep (two dependent L2 loads) from the critical path.
// Readers always use plain cached loads: each node line is written once
// pre-arrival and read only post-poll, never re-read.
// ---------------------------------------------------------------------------
__global__ __launch_bounds__(512) void tree_kernel(
    const __hip_bfloat16* __restrict__ WtG, const float* __restrict__ br,
    const __hip_bfloat16* __restrict__ leaf_h, const float* __restrict__ leaf_c,
    __hip_bfloat16* __restrict__ node_h, float* __restrict__ node_c,
    const int* __restrict__ node_l, const int* __restrict__ node_r,
    const int* __restrict__ root_src, const int* __restrict__ offs,
    const int* __restrict__ items, const int* __restrict__ max_lv,
    float* __restrict__ out, int* __restrict__ sync)
{
    __shared__ float Cs[8][8][84];    // per-kq MFMA partials (rows 0..7 real)
    __shared__ float Cred[8][84];     // reduced gates + bias
    __shared__ float brs[NC];
    // Static per-level metadata cache: [lev*8 + m] for lev 1..255, m 0..7.
    // Offsets are BYTE offsets; bit31 = node (vs leaf) buffer tag.
    __shared__ u32 mHL[2048], mHR[2048], mCL[2048], mCR[2048], mFL[2048];
    __shared__ u64 hPl[16], hPr[16], cPl[16], cPr[16];  // legacy (>8 items/level)
    __shared__ int outm[16];                            // legacy flags
    __shared__ int s_info;
    __shared__ int force_pad[5120];   // 20 KB: total LDS > 80 KB -> 1 block/CU

    const int tid = threadIdx.x;

    // ---- census: discover XCD, claim rank, decide protocol mode ----
    if (tid == 0) {
        int xcc;
        asm volatile("s_getreg_b32 %0, hwreg(HW_REG_XCC_ID)" : "=s"(xcc));
        xcc &= 7;
        const int rank = atomicAdd(&sync[2 + xcc], 1);
        __builtin_amdgcn_s_waitcnt(0);  // rank add acked before grid arrival
        const int n = atomicAdd(&sync[0], 1);
        if (n == 255) {
            int ok = 1;
            for (int i = 0; i < 8; i++)
                ok &= (__hip_atomic_load(&sync[2 + i], __ATOMIC_RELAXED,
                                         __HIP_MEMORY_SCOPE_AGENT) == NBLK);
            __hip_atomic_store(&sync[1], ok ? 2 : 1, __ATOMIC_RELAXED,
                               __HIP_MEMORY_SCOPE_AGENT);
        }
        int m;
        while ((m = __hip_atomic_load(&sync[1], __ATOMIC_RELAXED,
                                      __HIP_MEMORY_SCOPE_AGENT)) == 0) {}
        const int grp_ = (m == 2) ? xcc : ((int)blockIdx.x >> 5);
        const int mem_ = (m == 2) ? rank : ((int)blockIdx.x & 31);
        s_info = (m << 16) | (grp_ << 8) | mem_;
    }
    __syncthreads();
    const int info0 = s_info;
    const bool l2m = (info0 >> 16) == 2;
    const int grp = (info0 >> 8) & 255;
    const int mem = info0 & 255;
    const int j0 = mem * JPB;

    const int* offsG = offs + grp * 257;
    const int* itemsG = items + grp * (GBATCH * NNODE);
    int* cntG = sync + 16 + grp * 1024;

    const int ML = max_lv[grp];
    if (ML < 0) { volatile int* fp = force_pad; fp[tid] = 1; }  // keep pad live

    const int wave = tid >> 6;
    const int lane = tid & 63;
    const int quad = lane >> 4;
    const int l15 = lane & 15;
    const int kq = wave;  // K slice [kq*128, kq*128+128); kq<4 left child, else right

    u32* node_h32 = (u32*)node_h;
    const char* const hBaseL = (const char*)leaf_h;
    const char* const hBaseN = (const char*)node_h;
    const char* const cBaseL = (const char*)leaf_c;
    const char* const cBaseN = (const char*)node_c;

    // ---- W_r slice -> VGPRs ----
    v8bf wreg[5][4];
#pragma unroll
    for (int nt = 0; nt < 5; nt++) {
        const int c = nt * 16 + l15;
        const long gcol = (long)((c % 5) * Hh + j0 + c / 5);
#pragma unroll
        for (int t = 0; t < 4; t++)
            wreg[nt][t] = *(const v8bf*)&WtG[gcol * 1024 + kq * 128 + t * 32 + quad * 8];
    }
    if (tid < NC) brs[tid] = br[(tid % 5) * Hh + j0 + tid / 5];

    // ---- one-time metadata precompute (static schedule -> LDS) ----
    for (int idx = tid; idx < 255 * 8; idx += 512) {
        const int lev = 1 + (idx >> 3);
        const int m = idx & 7;
        u32 fl = 1u << 29;  // default: pad
        u32 hl = 0, hr = 0, cl = 0, cr = 0;
        if (lev <= ML) {
            const int s = offsG[lev], e = offsG[lev + 1];
            const int M = e - s;
            if (M > 0) {
                const int it = itemsG[s + (m < M ? m : 0)];
                const int b = it >> 16, nd = it & 0xffff;
                const int lraw = node_l[b * NNODE + nd];
                const int rraw = node_r[b * NNODE + nd];
                const int ls = lraw & 511, llv = lraw >> 9;
                const int rs = rraw & 511, rlv = rraw >> 9;
                hl = (ls < Tt) ? (u32)((b * Tt + ls) * Hh * 2)
                               : ((u32)((b * NNODE + (ls - Tt)) * Hh * 2) | 0x80000000u);
                cl = (ls < Tt) ? (u32)((b * Tt + ls) * Hh * 4)
                               : ((u32)((b * NNODE + (ls - Tt)) * Hh * 4) | 0x80000000u);
                hr = (rs < Tt) ? (u32)((b * Tt + rs) * Hh * 2)
                               : ((u32)((b * NNODE + (rs - Tt)) * Hh * 2) | 0x80000000u);
                cr = (rs < Tt) ? (u32)((b * Tt + rs) * Hh * 4)
                               : ((u32)((b * NNODE + (rs - Tt)) * Hh * 4) | 0x80000000u);
                fl = (u32)it & 0x07ffffffu;
                if (llv > 0 && llv == lev - 1) fl |= 1u << 27;  // hot left
                if (rlv > 0 && rlv == lev - 1) fl |= 1u << 28;  // hot right
                if (m >= M) fl |= 1u << 29;
                if (Tt + nd == root_src[b]) fl |= 1u << 30;
            }
        }
        mHL[8 + idx] = hl; mHR[8 + idx] = hr;
        mCL[8 + idx] = cl; mCR[8 + idx] = cr;
        mFL[8 + idx] = fl;
    }

    // legacy prep (only for rare >8-items-per-level chunks)
    auto prep = [&](int base, int M, int plv) {
        if (lane < 16) {
            const int m = lane;
            const int it = itemsG[base + (m < M ? m : 0)];
            const int b = it >> 16;
            const int nd = it & 0xffff;
            const int lraw = node_l[b * NNODE + nd];
            const int rraw = node_r[b * NNODE + nd];
            const int ls = lraw & 511, llv = lraw >> 9;
            const int rs = rraw & 511, rlv = rraw >> 9;
            hPl[m] = (ls < Tt) ? (u64)(leaf_h + ((long)b * Tt + ls) * Hh)
                               : (u64)(node_h + ((long)b * NNODE + (ls - Tt)) * Hh);
            cPl[m] = (ls < Tt) ? (u64)(leaf_c + ((long)b * Tt + ls) * Hh)
                               : (u64)(node_c + ((long)b * NNODE + (ls - Tt)) * Hh);
            hPr[m] = (rs < Tt) ? (u64)(leaf_h + ((long)b * Tt + rs) * Hh)
                               : (u64)(node_h + ((long)b * NNODE + (rs - Tt)) * Hh);
            cPr[m] = (rs < Tt) ? (u64)(leaf_c + ((long)b * Tt + rs) * Hh)
                               : (u64)(node_c + ((long)b * NNODE + (rs - Tt)) * Hh);
            int fl = it;
            if (llv > 0 && llv == plv - 1) fl |= (1 << 27);
            if (rlv > 0 && rlv == plv - 1) fl |= (1 << 28);
            if (Tt + nd == root_src[b]) fl |= (1 << 30);
            if (m >= M) fl |= (1 << 29);
            outm[m] = fl;
        }
    };

    // Gate math + h/c store for one flags word (wave 0; lane -> m=lane>>3).
    auto gate_store = [&](u32 fe, float clv0, float clv1, float crv0, float crv1) {
        const int jl2 = (lane & 7) * 2;
        if (!(fe & (1u << 29))) {
            const int b = (int)(fe >> 16) & 63;
            const int nd = (int)(fe & 0xffff);
            float cv[2], hv[2];
            const float clv[2] = {clv0, clv1};
            const float crv[2] = {crv0, crv1};
            const int mm = lane >> 3;
#pragma unroll
            for (int jj = 0; jj < 2; jj++) {
                const int jc = (jl2 + jj) * 5;
                const float iv = Cred[mm][jc + 0];
                const float fl = Cred[mm][jc + 1];
                const float fr = Cred[mm][jc + 2];
                const float gv = Cred[mm][jc + 3];
                const float ov = Cred[mm][jc + 4];
                cv[jj] = sigm(iv) * tanhf(gv) + sigm(fl) * clv[jj] + sigm(fr) * crv[jj];
                hv[jj] = sigm(ov) * tanhf(cv[jj]);
            }
            union { float f[2]; u64 u; } cp;
            cp.f[0] = cv[0]; cp.f[1] = cv[1];
            const __hip_bfloat16 h0 = __float2bfloat16(hv[0]);
            const __hip_bfloat16 h1 = __float2bfloat16(hv[1]);
            const u32 hpack = (u32)(*(const unsigned short*)&h0)
                            | ((u32)(*(const unsigned short*)&h1) << 16);
            u64* cdst = (u64*)(node_c + ((long)b * NNODE + nd) * Hh + j0 + jl2);
            u32* hdst = node_h32 + ((long)b * NNODE + nd) * (Hh / 2) + (j0 + jl2) / 2;
            if (l2m) {
                *cdst = cp.u;   // plain: lands in this XCD's shared L2
                *hdst = hpack;
            } else {
                __hip_atomic_store(cdst, cp.u, __ATOMIC_RELAXED, __HIP_MEMORY_SCOPE_AGENT);
                __hip_atomic_store(hdst, hpack, __ATOMIC_RELAXED, __HIP_MEMORY_SCOPE_AGENT);
            }
            if (fe & (1u << 30)) {
                out[(long)b * Hh + j0 + jl2]     = hv[0];
                out[(long)b * Hh + j0 + jl2 + 1] = hv[1];
            }
        }
    };

    // MFMA for current chunk from registers; B operands from wreg (VGPR).
    auto do_mfma = [&](v8bf a0, v8bf a1, v8bf a2, v8bf a3) {
        v8bf a[4] = {a0, a1, a2, a3};
#pragma unroll
        for (int nt = 0; nt < 5; nt++) {
            v4f acc = {0.f, 0.f, 0.f, 0.f};
#pragma unroll
            for (int t = 0; t < 4; t++)
                acc = __builtin_amdgcn_mfma_f32_16x16x32_bf16(a[t], wreg[nt][t], acc, 0, 0, 0);
            if (quad < 2) {
#pragma unroll
                for (int rg = 0; rg < 4; rg++)
                    Cs[kq][quad * 4 + rg][nt * 16 + l15] = acc[rg];
            }
        }
    };

    // Reduce Cs over kq + bias -> Cred (all 512 threads).
    auto reduce = [&]() {
        for (int t = tid; t < 8 * NC; t += 512) {
            const int m = t / NC, c = t - m * NC;
            float r = brs[c];
#pragma unroll
            for (int w = 0; w < 8; w++) r += Cs[w][m][c];
            Cred[m][c] = r;
        }
    };

    __syncthreads();  // meta cache + brs visible

    const int kb = (kq & 3) * 128 + quad * 8;

    for (int lev = 1; lev <= ML; lev++) {
        const int s = offsG[lev], e = offsG[lev + 1];
        const int mb = lev * 8;

        // ---- Phase A (pre-poll): meta from LDS + cold child gather ----
        const int miA = mb + (l15 & 7);
        const u32 flA = mFL[miA];
        const bool hot = (flA >> (27 + (kq >> 2))) & 1;
        const u32 ho = (kq < 4) ? mHL[miA] : mHR[miA];
        const __hip_bfloat16* hp = (const __hip_bfloat16*)
            (((ho & 0x80000000u) ? hBaseN : hBaseL) + (ho & 0x7fffffffu));
        v8bf a0, a1, a2, a3;
        if (!hot) {
            a0 = *(const v8bf*)(hp + kb);
            a1 = *(const v8bf*)(hp + kb + 32);
            a2 = *(const v8bf*)(hp + kb + 64);
            a3 = *(const v8bf*)(hp + kb + 96);
        }
        float clv0 = 0.f, clv1 = 0.f, crv0 = 0.f, crv1 = 0.f;
        bool hotL = false, hotR = false;
        u32 fe = 0;
        const float* cpl = nullptr;
        const float* cpr = nullptr;
        if (wave == 0) {
            const int mi0 = mb + (lane >> 3);
            fe = mFL[mi0];
            hotL = (fe >> 27) & 1;
            hotR = (fe >> 28) & 1;
            const u32 ocl = mCL[mi0], ocr = mCR[mi0];
            cpl = (const float*)(((ocl & 0x80000000u) ? cBaseN : cBaseL) + (ocl & 0x7fffffffu));
            cpr = (const float*)(((ocr & 0x80000000u) ? cBaseN : cBaseL) + (ocr & 0x7fffffffu));
            const int jo = j0 + (lane & 7) * 2;
            if (!hotL) {
                union { u64 u; float f[2]; } t;
                t.u = *(const u64*)(cpl + jo);
                clv0 = t.f[0]; clv1 = t.f[1];
            }
            if (!hotR) {
                union { u64 u; float f[2]; } t;
                t.u = *(const u64*)(cpr + jo);
                crv0 = t.f[0]; crv1 = t.f[1];
            }
        }

        // ---- Barrier: wave 0 polls this group's level counter (LLC) ----
        if (lev > 1 && wave == 0) {
            int* cw = cntG + (lev - 1) * 4;
            while (__hip_atomic_load(cw, __ATOMIC_RELAXED,
                                     __HIP_MEMORY_SCOPE_AGENT) < NBLK) {}
        }
        __syncthreads();

        // ---- Phase B (post-poll): hot gather + MFMA ----
        if (hot) {
            a0 = *(const v8bf*)(hp + kb);
            a1 = *(const v8bf*)(hp + kb + 32);
            a2 = *(const v8bf*)(hp + kb + 64);
            a3 = *(const v8bf*)(hp + kb + 96);
        }
        if (wave == 0) {
            const int jo = j0 + (lane & 7) * 2;
            if (hotL) {
                union { u64 u; float f[2]; } t;
                t.u = *(const u64*)(cpl + jo);
                clv0 = t.f[0]; clv1 = t.f[1];
            }
            if (hotR) {
                union { u64 u; float f[2]; } t;
                t.u = *(const u64*)(cpr + jo);
                crv0 = t.f[0]; crv1 = t.f[1];
            }
        }
        do_mfma(a0, a1, a2, a3);
        __syncthreads();
        reduce();
        __syncthreads();
        if (wave == 0) gate_store(fe, clv0, clv1, crv0, crv1);

        // ---- Rare extra chunks (>8 items/level): legacy generic path ----
        for (int base = s + 8; base < e; base += 8) {
            __syncthreads();
            if (wave == 0) prep(base, (e - base < 8) ? (e - base) : 8, lev);
            __syncthreads();
            const __hip_bfloat16* hp2 =
                (const __hip_bfloat16*)((kq < 4) ? hPl[l15 & 7] : hPr[l15 & 7]);
            float xl0 = 0.f, xl1 = 0.f, xr0 = 0.f, xr1 = 0.f;
            u32 fe2 = 1u << 29;
            if (wave == 0) {
                fe2 = (u32)outm[lane >> 3];
                const int jo = j0 + (lane & 7) * 2;
                union { u64 u; float f[2]; } t;
                t.u = *(const u64*)((const float*)cPl[lane >> 3] + jo);
                xl0 = t.f[0]; xl1 = t.f[1];
                t.u = *(const u64*)((const float*)cPr[lane >> 3] + jo);
                xr0 = t.f[0]; xr1 = t.f[1];
            }
            do_mfma(*(const v8bf*)(hp2 + kb), *(const v8bf*)(hp2 + kb + 32),
                    *(const v8bf*)(hp2 + kb + 64), *(const v8bf*)(hp2 + kb + 96));
            __syncthreads();
            reduce();
            __syncthreads();
            if (wave == 0) gate_store(fe2, xl0, xl1, xr0, xr1);
        }

        // ---- Arrival (stores acked first); R1-proven protocol ----
        if (wave == 0) {
            __builtin_amdgcn_s_waitcnt(0);  // drain wave-0 h/c stores (L2 or LLC ack)
            if (lev < ML && lane == 0) atomicAdd(cntG + lev * 4, 1);
        }
        __syncthreads();
    }
}

// ---------------------------------------------------------------------------
extern "C" void kernel_launch(void* const* d_in, const int* in_sizes, int n_in,
                              void* d_out, int out_size, void* d_ws, size_t ws_size,
                              hipStream_t stream)
{
    const float* x   = (const float*)d_in[0];
    const int* trans = (const int*)d_in[1];
    const float* Wx  = (const float*)d_in[2];
    const float* bx  = (const float*)d_in[3];
    const float* Wg  = (const float*)d_in[4];
    const float* bg  = (const float*)d_in[5];
    const float* Wr  = (const float*)d_in[6];
    const float* br  = (const float*)d_in[7];
    float* out = (float*)d_out;

    char* p = (char*)d_ws;
    auto take = [&](size_t bytes) -> char* {
        char* r = p;
        p += (bytes + 255) & ~(size_t)255;
        return r;
    };
    __hip_bfloat16* leaf_h = (__hip_bfloat16*)take((size_t)Bb * Tt * Hh * 2);
    float* leaf_c          = (float*)take((size_t)Bb * Tt * Hh * 4);
    __hip_bfloat16* node_h = (__hip_bfloat16*)take((size_t)Bb * NNODE * Hh * 2);
    float* node_c          = (float*)take((size_t)Bb * NNODE * Hh * 4);
    int* node_l   = (int*)take((size_t)Bb * NNODE * 4);
    int* node_r   = (int*)take((size_t)Bb * NNODE * 4);
    int* root_src = (int*)take(Bb * 4);
    int* offs     = (int*)take((size_t)NG * 257 * 4);
    int* items    = (int*)take((size_t)NG * GBATCH * NNODE * 4);
    int* max_lv   = (int*)take(NG * 4);
    __hip_bfloat16* WtG = (__hip_bfloat16*)take((size_t)N5H * 1024 * 2);
    int* sync     = (int*)take((size_t)SYNC_INTS * 4);

    hipLaunchKernelGGL(leaf_kernel, dim3(Hh / 256, (Bb * Tt) / 16), dim3(256), 0, stream,
                       x, Wx, bx, Wg, bg, leaf_h, leaf_c);
    hipLaunchKernelGGL(wtr_kernel, dim3(N5H / 64, 1024 / 64), dim3(256), 0, stream,
                       Wr, WtG);
    hipLaunchKernelGGL(sched_kernel, dim3(1), dim3(64), 0, stream,
                       trans, node_l, node_r, root_src, offs, items, max_lv, sync);

    void* args[] = { (void*)&WtG, (void*)&br, (void*)&leaf_h, (void*)&leaf_c,
                     (void*)&node_h, (void*)&node_c, (void*)&node_l, (void*)&node_r,
                     (void*)&root_src, (void*)&offs, (void*)&items, (void*)&max_lv,
                     (void*)&out, (void*)&sync };
    hipLaunchCooperativeKernel((const void*)tree_kernel, dim3(256), dim3(512),
                               args, 0, stream);
}

// Round 5
// 1252.085 us; speedup vs baseline: 1.3341x; 1.0061x over previous
//
#include <hip/hip_runtime.h>
#include <hip/hip_bf16.h>

// Problem constants (match reference setup_inputs)
#define Bb 64
#define Tt 256
#define Ee 300
#define Hh 512
#define NSTEP (2 * Tt - 1)  // 511
#define NNODE (Tt - 1)      // 255
#define N5H (5 * Hh)        // 2560

// Group decomposition: 8 groups x 32 blocks; each group owns 8 batches
// end-to-end and (in fast mode) lives on ONE XCD so node h/c handoff goes
// through the XCD-local L2. Block = member 'mem' owns 16 j-cols; its W_r
// slice (80 gate-cols x K=1024, bf16) lives in VGPRs.
#define NG 8
#define GBATCH 8
#define NBLK 32
#define JPB 16
#define NC 80   // JPB * 5 gate-cols per block
// sync area: [0]=grid arrival, [1]=mode (0 unset / 1 LLC / 2 XCD-local),
// [2..9]=per-XCD census counts, [16 + g*1024 + mem*16] = per-group
// PER-MEMBER level flags (64 B apart -> no line sharing; arrival is a plain
// agent store of 'lev', NOT an RMW, so 32 arrivals land in parallel instead
// of serializing at one LLC line). Flags monotone within a run; zeroed by
// sched_kernel each launch (R0/R1-proven path). Agent scope in both modes.
#define SYNC_INTS (16 + NG * 1024)

typedef __bf16 v8bf __attribute__((ext_vector_type(8)));
typedef float v4f __attribute__((ext_vector_type(4)));
typedef unsigned long long u64;
typedef unsigned int u32;
typedef unsigned char u8;

__device__ __forceinline__ float sigm(float x) { return 1.f / (1.f + __expf(-x)); }

// ---------------------------------------------------------------------------
// Phase 1: leaf buffer projections (unchanged, proven).
// ---------------------------------------------------------------------------
__global__ __launch_bounds__(256) void leaf_kernel(
    const float* __restrict__ x, const float* __restrict__ Wx,
    const float* __restrict__ bx, const float* __restrict__ Wg,
    const float* __restrict__ bg,
    __hip_bfloat16* __restrict__ leaf_h, float* __restrict__ leaf_c)
{
    __shared__ __align__(16) float xs[16][304];
    const int tid = threadIdx.x;
    const int n = blockIdx.x * 256 + tid;
    const long r0 = (long)blockIdx.y * 16;

    for (int i = tid; i < 16 * Ee; i += 256) {
        int r = i / Ee, k = i - r * Ee;
        xs[r][k] = x[(r0 + r) * Ee + k];
    }
    __syncthreads();

    float accx[16], accg[16];
    const float bxv = bx[n], bgv = bg[n];
#pragma unroll
    for (int r = 0; r < 16; r++) { accx[r] = bxv; accg[r] = bgv; }

    for (int k = 0; k < Ee; k += 4) {
        float wx[4], wg[4];
#pragma unroll
        for (int u = 0; u < 4; u++) {
            wx[u] = Wx[(long)(k + u) * Hh + n];
            wg[u] = Wg[(long)(k + u) * Hh + n];
        }
#pragma unroll
        for (int r = 0; r < 16; r++) {
            const float4 xv = *(const float4*)&xs[r][k];
            accx[r] = fmaf(xv.x, wx[0], accx[r]);
            accx[r] = fmaf(xv.y, wx[1], accx[r]);
            accx[r] = fmaf(xv.z, wx[2], accx[r]);
            accx[r] = fmaf(xv.w, wx[3], accx[r]);
            accg[r] = fmaf(xv.x, wg[0], accg[r]);
            accg[r] = fmaf(xv.y, wg[1], accg[r]);
            accg[r] = fmaf(xv.z, wg[2], accg[r]);
            accg[r] = fmaf(xv.w, wg[3], accg[r]);
        }
    }
#pragma unroll
    for (int r = 0; r < 16; r++) {
        const float c = accx[r];
        const float h = sigm(accg[r]) * tanhf(c);
        const long idx = (r0 + r) * Hh + n;
        leaf_c[idx] = c;
        leaf_h[idx] = __float2bfloat16(h);
    }
}

// ---------------------------------------------------------------------------
// Phase 1b: pre-transpose W_r -> WtG[gc][k] bf16 (coalesced both sides).
// ---------------------------------------------------------------------------
__global__ __launch_bounds__(256) void wtr_kernel(const float* __restrict__ Wr,
                                                  __hip_bfloat16* __restrict__ WtG)
{
    __shared__ float ts[64][65];
    const int tid = threadIdx.x;
    const long g0 = (long)blockIdx.x * 64;  // gate-col tile (2560/64 = 40)
    const int k0 = (int)blockIdx.y * 64;    // k tile       (1024/64 = 16)
    const int r = tid >> 6;                 // 0..3
    const int c = tid & 63;
    __bf16* Wo = (__bf16*)WtG;
#pragma unroll
    for (int i = 0; i < 16; i++)
        ts[r + i * 4][c] = Wr[(long)(k0 + r + i * 4) * N5H + g0 + c];
    __syncthreads();
#pragma unroll
    for (int i = 0; i < 16; i++)
        Wo[(g0 + r + i * 4) * 1024 + k0 + c] = (__bf16)ts[c][r + i * 4];
}

// ---------------------------------------------------------------------------
// Phase 2: schedule. Per-GROUP (8 batches) level buckets. Zeros the sync area.
// ---------------------------------------------------------------------------
__global__ __launch_bounds__(64) void sched_kernel(
    const int* __restrict__ trans,
    int* __restrict__ node_l, int* __restrict__ node_r,
    int* __restrict__ root_src, int* __restrict__ offs,   // [NG*257]
    int* __restrict__ items, int* __restrict__ max_lv,    // [NG*GBATCH*NNODE], [NG]
    int* __restrict__ sync)                               // SYNC_INTS ints
{
    __shared__ short stck[Bb][Tt];
    __shared__ unsigned char lvl[Bb][NNODE];
    __shared__ unsigned char trans_s[NSTEP][Bb];
    __shared__ int counts[NG][256];
    __shared__ int offs_s[NG][257];
    __shared__ int maxl_s[NG];
    const int b = threadIdx.x;

    if (b < NG) maxl_s[b] = 0;
    for (int i4 = b; i4 < SYNC_INTS / 4; i4 += Bb)
        ((int4*)sync)[i4] = make_int4(0, 0, 0, 0);
    for (int i = b; i < NG * 256; i += Bb) counts[i >> 8][i & 255] = 0;
    for (int i4 = b; i4 < (NSTEP * Bb) / 4; i4 += Bb) {
        const int4 v = ((const int4*)trans)[i4];
        const int f = 4 * i4;
        trans_s[(f + 0) >> 6][(f + 0) & 63] = (unsigned char)v.x;
        trans_s[(f + 1) >> 6][(f + 1) & 63] = (unsigned char)v.y;
        trans_s[(f + 2) >> 6][(f + 2) & 63] = (unsigned char)v.z;
        trans_s[(f + 3) >> 6][(f + 3) & 63] = (unsigned char)v.w;
    }
    __syncthreads();

    int sp = 0, bp = Tt, nid = 0, maxl = 0;
    for (int t = 0; t < NSTEP; t++) {
        if (trans_s[t][b] == 0) {
            bp -= 1;
            stck[b][sp] = (short)bp; sp += 1;
        } else {
            const int rs = stck[b][sp - 1];
            const int ls = stck[b][sp - 2];
            const int l_lv = (ls < Tt) ? 0 : (int)lvl[b][ls - Tt];
            const int r_lv = (rs < Tt) ? 0 : (int)lvl[b][rs - Tt];
            const int le = 1 + (l_lv > r_lv ? l_lv : r_lv);
            lvl[b][nid] = (unsigned char)le;
            node_l[b * NNODE + nid] = (l_lv << 9) | ls;
            node_r[b * NNODE + nid] = (r_lv << 9) | rs;
            if (le > maxl) maxl = le;
            sp -= 2;
            stck[b][sp] = (short)(Tt + nid); sp += 1;
            nid += 1;
        }
    }
    root_src[b] = (int)stck[b][0];
    const int g = b >> 3;  // group of this batch (8 batches/group)
    for (int i = 0; i < nid; i++) atomicAdd(&counts[g][lvl[b][i]], 1);
    atomicMax(&maxl_s[g], maxl);
    __syncthreads();
    if (b < NG) {
        int acc = 0;
        for (int l = 0; l < 256; l++) { offs_s[b][l] = acc; acc += counts[b][l]; }
        offs_s[b][256] = acc;
        max_lv[b] = maxl_s[b];
    }
    __syncthreads();
    for (int i = b; i < NG * 256; i += Bb) counts[i >> 8][i & 255] = offs_s[i >> 8][i & 255];
    __syncthreads();
    for (int i = 0; i < nid; i++) {
        const int pos = atomicAdd(&counts[g][lvl[b][i]], 1);
        items[g * (GBATCH * NNODE) + pos] = (b << 16) | i;
    }
    for (int i = b; i < NG * 257; i += Bb) offs[i] = offs_s[i / 257][i % 257];
}

// ---------------------------------------------------------------------------
// Phase 3: 8 groups x 32 blocks. W_r in VGPRs. Census via HW_REG_XCC_ID:
// mode 2 (each XCD hosts exactly one 32-block group) -> node h/c plain cached
// stores (write-through -> XCD L2). Mode 1 fallback: agent-scope (LLC)
// stores. Level-barrier: per-member level-stamped flag words (64 B apart):
// arrival = plain agent-scope relaxed STORE of lev (no RMW -> 32 arrivals in
// parallel, no LLC serialization); poll = wave-0 lanes 0..31 each load one
// member's flag, __all(v >= lev-1). Static schedule precomputed once into a
// 40 KB LDS metadata cache. Readers use plain cached loads: each node line
// is written once pre-arrival and read only post-poll, never re-read.
// ---------------------------------------------------------------------------
__global__ __launch_bounds__(512) void tree_kernel(
    const __hip_bfloat16* __restrict__ WtG, const float* __restrict__ br,
    const __hip_bfloat16* __restrict__ leaf_h, const float* __restrict__ leaf_c,
    __hip_bfloat16* __restrict__ node_h, float* __restrict__ node_c,
    const int* __restrict__ node_l, const int* __restrict__ node_r,
    const int* __restrict__ root_src, const int* __restrict__ offs,
    const int* __restrict__ items, const int* __restrict__ max_lv,
    float* __restrict__ out, int* __restrict__ sync)
{
    __shared__ float Cs[8][8][84];    // per-kq MFMA partials (rows 0..7 real)
    __shared__ float Cred[8][84];     // reduced gates + bias
    __shared__ float brs[NC];
    // Static per-level metadata cache: [lev*8 + m] for lev 1..255, m 0..7.
    // Offsets are BYTE offsets; bit31 = node (vs leaf) buffer tag.
    __shared__ u32 mHL[2048], mHR[2048], mCL[2048], mCR[2048], mFL[2048];
    __shared__ u64 hPl[16], hPr[16], cPl[16], cPr[16];  // legacy (>8 items/level)
    __shared__ int outm[16];                            // legacy flags
    __shared__ int s_info;
    __shared__ int force_pad[5120];   // 20 KB: total LDS > 80 KB -> 1 block/CU

    const int tid = threadIdx.x;

    // ---- census: discover XCD, claim rank, decide protocol mode ----
    if (tid == 0) {
        int xcc;
        asm volatile("s_getreg_b32 %0, hwreg(HW_REG_XCC_ID)" : "=s"(xcc));
        xcc &= 7;
        const int rank = atomicAdd(&sync[2 + xcc], 1);
        __builtin_amdgcn_s_waitcnt(0);  // rank add acked before grid arrival
        const int n = atomicAdd(&sync[0], 1);
        if (n == 255) {
            int ok = 1;
            for (int i = 0; i < 8; i++)
                ok &= (__hip_atomic_load(&sync[2 + i], __ATOMIC_RELAXED,
                                         __HIP_MEMORY_SCOPE_AGENT) == NBLK);
            __hip_atomic_store(&sync[1], ok ? 2 : 1, __ATOMIC_RELAXED,
                               __HIP_MEMORY_SCOPE_AGENT);
        }
        int m;
        while ((m = __hip_atomic_load(&sync[1], __ATOMIC_RELAXED,
                                      __HIP_MEMORY_SCOPE_AGENT)) == 0) {}
        const int grp_ = (m == 2) ? xcc : ((int)blockIdx.x >> 5);
        const int mem_ = (m == 2) ? rank : ((int)blockIdx.x & 31);
        s_info = (m << 16) | (grp_ << 8) | mem_;
    }
    __syncthreads();
    const int info0 = s_info;
    const bool l2m = (info0 >> 16) == 2;
    const int grp = (info0 >> 8) & 255;
    const int mem = info0 & 255;
    const int j0 = mem * JPB;

    const int* offsG = offs + grp * 257;
    const int* itemsG = items + grp * (GBATCH * NNODE);
    int* flagG = sync + 16 + grp * 1024;   // member m's flag at flagG[m*16]

    const int ML = max_lv[grp];
    if (ML < 0) { volatile int* fp = force_pad; fp[tid] = 1; }  // keep pad live

    const int wave = tid >> 6;
    const int lane = tid & 63;
    const int quad = lane >> 4;
    const int l15 = lane & 15;
    const int kq = wave;  // K slice [kq*128, kq*128+128); kq<4 left child, else right

    u32* node_h32 = (u32*)node_h;
    const char* const hBaseL = (const char*)leaf_h;
    const char* const hBaseN = (const char*)node_h;
    const char* const cBaseL = (const char*)leaf_c;
    const char* const cBaseN = (const char*)node_c;

    // ---- W_r slice -> VGPRs ----
    v8bf wreg[5][4];
#pragma unroll
    for (int nt = 0; nt < 5; nt++) {
        const int c = nt * 16 + l15;
        const long gcol = (long)((c % 5) * Hh + j0 + c / 5);
#pragma unroll
        for (int t = 0; t < 4; t++)
            wreg[nt][t] = *(const v8bf*)&WtG[gcol * 1024 + kq * 128 + t * 32 + quad * 8];
    }
    if (tid < NC) brs[tid] = br[(tid % 5) * Hh + j0 + tid / 5];

    // ---- one-time metadata precompute (static schedule -> LDS) ----
    for (int idx = tid; idx < 255 * 8; idx += 512) {
        const int lev = 1 + (idx >> 3);
        const int m = idx & 7;
        u32 fl = 1u << 29;  // default: pad
        u32 hl = 0, hr = 0, cl = 0, cr = 0;
        if (lev <= ML) {
            const int s = offsG[lev], e = offsG[lev + 1];
            const int M = e - s;
            if (M > 0) {
                const int it = itemsG[s + (m < M ? m : 0)];
                const int b = it >> 16, nd = it & 0xffff;
                const int lraw = node_l[b * NNODE + nd];
                const int rraw = node_r[b * NNODE + nd];
                const int ls = lraw & 511, llv = lraw >> 9;
                const int rs = rraw & 511, rlv = rraw >> 9;
                hl = (ls < Tt) ? (u32)((b * Tt + ls) * Hh * 2)
                               : ((u32)((b * NNODE + (ls - Tt)) * Hh * 2) | 0x80000000u);
                cl = (ls < Tt) ? (u32)((b * Tt + ls) * Hh * 4)
                               : ((u32)((b * NNODE + (ls - Tt)) * Hh * 4) | 0x80000000u);
                hr = (rs < Tt) ? (u32)((b * Tt + rs) * Hh * 2)
                               : ((u32)((b * NNODE + (rs - Tt)) * Hh * 2) | 0x80000000u);
                cr = (rs < Tt) ? (u32)((b * Tt + rs) * Hh * 4)
                               : ((u32)((b * NNODE + (rs - Tt)) * Hh * 4) | 0x80000000u);
                fl = (u32)it & 0x07ffffffu;
                if (llv > 0 && llv == lev - 1) fl |= 1u << 27;  // hot left
                if (rlv > 0 && rlv == lev - 1) fl |= 1u << 28;  // hot right
                if (m >= M) fl |= 1u << 29;
                if (Tt + nd == root_src[b]) fl |= 1u << 30;
            }
        }
        mHL[8 + idx] = hl; mHR[8 + idx] = hr;
        mCL[8 + idx] = cl; mCR[8 + idx] = cr;
        mFL[8 + idx] = fl;
    }

    // legacy prep (only for rare >8-items-per-level chunks)
    auto prep = [&](int base, int M, int plv) {
        if (lane < 16) {
            const int m = lane;
            const int it = itemsG[base + (m < M ? m : 0)];
            const int b = it >> 16;
            const int nd = it & 0xffff;
            const int lraw = node_l[b * NNODE + nd];
            const int rraw = node_r[b * NNODE + nd];
            const int ls = lraw & 511, llv = lraw >> 9;
            const int rs = rraw & 511, rlv = rraw >> 9;
            hPl[m] = (ls < Tt) ? (u64)(leaf_h + ((long)b * Tt + ls) * Hh)
                               : (u64)(node_h + ((long)b * NNODE + (ls - Tt)) * Hh);
            cPl[m] = (ls < Tt) ? (u64)(leaf_c + ((long)b * Tt + ls) * Hh)
                               : (u64)(node_c + ((long)b * NNODE + (ls - Tt)) * Hh);
            hPr[m] = (rs < Tt) ? (u64)(leaf_h + ((long)b * Tt + rs) * Hh)
                               : (u64)(node_h + ((long)b * NNODE + (rs - Tt)) * Hh);
            cPr[m] = (rs < Tt) ? (u64)(leaf_c + ((long)b * Tt + rs) * Hh)
                               : (u64)(node_c + ((long)b * NNODE + (rs - Tt)) * Hh);
            int fl = it;
            if (llv > 0 && llv == plv - 1) fl |= (1 << 27);
            if (rlv > 0 && rlv == plv - 1) fl |= (1 << 28);
            if (Tt + nd == root_src[b]) fl |= (1 << 30);
            if (m >= M) fl |= (1 << 29);
            outm[m] = fl;
        }
    };

    // Gate math + h/c store for one flags word (wave 0; lane -> m=lane>>3).
    auto gate_store = [&](u32 fe, float clv0, float clv1, float crv0, float crv1) {
        const int jl2 = (lane & 7) * 2;
        if (!(fe & (1u << 29))) {
            const int b = (int)(fe >> 16) & 63;
            const int nd = (int)(fe & 0xffff);
            float cv[2], hv[2];
            const float clv[2] = {clv0, clv1};
            const float crv[2] = {crv0, crv1};
            const int mm = lane >> 3;
#pragma unroll
            for (int jj = 0; jj < 2; jj++) {
                const int jc = (jl2 + jj) * 5;
                const float iv = Cred[mm][jc + 0];
                const float fl = Cred[mm][jc + 1];
                const float fr = Cred[mm][jc + 2];
                const float gv = Cred[mm][jc + 3];
                const float ov = Cred[mm][jc + 4];
                cv[jj] = sigm(iv) * tanhf(gv) + sigm(fl) * clv[jj] + sigm(fr) * crv[jj];
                hv[jj] = sigm(ov) * tanhf(cv[jj]);
            }
            union { float f[2]; u64 u; } cp;
            cp.f[0] = cv[0]; cp.f[1] = cv[1];
            const __hip_bfloat16 h0 = __float2bfloat16(hv[0]);
            const __hip_bfloat16 h1 = __float2bfloat16(hv[1]);
            const u32 hpack = (u32)(*(const unsigned short*)&h0)
                            | ((u32)(*(const unsigned short*)&h1) << 16);
            u64* cdst = (u64*)(node_c + ((long)b * NNODE + nd) * Hh + j0 + jl2);
            u32* hdst = node_h32 + ((long)b * NNODE + nd) * (Hh / 2) + (j0 + jl2) / 2;
            if (l2m) {
                *cdst = cp.u;   // plain: lands in this XCD's shared L2
                *hdst = hpack;
            } else {
                __hip_atomic_store(cdst, cp.u, __ATOMIC_RELAXED, __HIP_MEMORY_SCOPE_AGENT);
                __hip_atomic_store(hdst, hpack, __ATOMIC_RELAXED, __HIP_MEMORY_SCOPE_AGENT);
            }
            if (fe & (1u << 30)) {
                out[(long)b * Hh + j0 + jl2]     = hv[0];
                out[(long)b * Hh + j0 + jl2 + 1] = hv[1];
            }
        }
    };

    // MFMA for current chunk from registers; B operands from wreg (VGPR).
    auto do_mfma = [&](v8bf a0, v8bf a1, v8bf a2, v8bf a3) {
        v8bf a[4] = {a0, a1, a2, a3};
#pragma unroll
        for (int nt = 0; nt < 5; nt++) {
            v4f acc = {0.f, 0.f, 0.f, 0.f};
#pragma unroll
            for (int t = 0; t < 4; t++)
                acc = __builtin_amdgcn_mfma_f32_16x16x32_bf16(a[t], wreg[nt][t], acc, 0, 0, 0);
            if (quad < 2) {
#pragma unroll
                for (int rg = 0; rg < 4; rg++)
                    Cs[kq][quad * 4 + rg][nt * 16 + l15] = acc[rg];
            }
        }
    };

    // Reduce Cs over kq + bias -> Cred (all 512 threads).
    auto reduce = [&]() {
        for (int t = tid; t < 8 * NC; t += 512) {
            const int m = t / NC, c = t - m * NC;
            float r = brs[c];
#pragma unroll
            for (int w = 0; w < 8; w++) r += Cs[w][m][c];
            Cred[m][c] = r;
        }
    };

    __syncthreads();  // meta cache + brs visible

    const int kb = (kq & 3) * 128 + quad * 8;

    for (int lev = 1; lev <= ML; lev++) {
        const int s = offsG[lev], e = offsG[lev + 1];
        const int mb = lev * 8;

        // ---- Phase A (pre-poll): meta from LDS + cold child gather ----
        const int miA = mb + (l15 & 7);
        const u32 flA = mFL[miA];
        const bool hot = (flA >> (27 + (kq >> 2))) & 1;
        const u32 ho = (kq < 4) ? mHL[miA] : mHR[miA];
        const __hip_bfloat16* hp = (const __hip_bfloat16*)
            (((ho & 0x80000000u) ? hBaseN : hBaseL) + (ho & 0x7fffffffu));
        v8bf a0, a1, a2, a3;
        if (!hot) {
            a0 = *(const v8bf*)(hp + kb);
            a1 = *(const v8bf*)(hp + kb + 32);
            a2 = *(const v8bf*)(hp + kb + 64);
            a3 = *(const v8bf*)(hp + kb + 96);
        }
        float clv0 = 0.f, clv1 = 0.f, crv0 = 0.f, crv1 = 0.f;
        bool hotL = false, hotR = false;
        u32 fe = 0;
        const float* cpl = nullptr;
        const float* cpr = nullptr;
        if (wave == 0) {
            const int mi0 = mb + (lane >> 3);
            fe = mFL[mi0];
            hotL = (fe >> 27) & 1;
            hotR = (fe >> 28) & 1;
            const u32 ocl = mCL[mi0], ocr = mCR[mi0];
            cpl = (const float*)(((ocl & 0x80000000u) ? cBaseN : cBaseL) + (ocl & 0x7fffffffu));
            cpr = (const float*)(((ocr & 0x80000000u) ? cBaseN : cBaseL) + (ocr & 0x7fffffffu));
            const int jo = j0 + (lane & 7) * 2;
            if (!hotL) {
                union { u64 u; float f[2]; } t;
                t.u = *(const u64*)(cpl + jo);
                clv0 = t.f[0]; clv1 = t.f[1];
            }
            if (!hotR) {
                union { u64 u; float f[2]; } t;
                t.u = *(const u64*)(cpr + jo);
                crv0 = t.f[0]; crv1 = t.f[1];
            }
        }

        // ---- Barrier: wave 0 polls all 32 member flags (parallel loads) ----
        if (lev > 1 && wave == 0) {
            const int need = lev - 1;
            const int* fp = flagG + (lane & 31) * 16;
            for (;;) {
                const int v = __hip_atomic_load(fp, __ATOMIC_RELAXED,
                                                __HIP_MEMORY_SCOPE_AGENT);
                if (__all(v >= need)) break;
            }
        }
        __syncthreads();

        // ---- Phase B (post-poll): hot gather + MFMA ----
        if (hot) {
            a0 = *(const v8bf*)(hp + kb);
            a1 = *(const v8bf*)(hp + kb + 32);
            a2 = *(const v8bf*)(hp + kb + 64);
            a3 = *(const v8bf*)(hp + kb + 96);
        }
        if (wave == 0) {
            const int jo = j0 + (lane & 7) * 2;
            if (hotL) {
                union { u64 u; float f[2]; } t;
                t.u = *(const u64*)(cpl + jo);
                clv0 = t.f[0]; clv1 = t.f[1];
            }
            if (hotR) {
                union { u64 u; float f[2]; } t;
                t.u = *(const u64*)(cpr + jo);
                crv0 = t.f[0]; crv1 = t.f[1];
            }
        }
        do_mfma(a0, a1, a2, a3);
        __syncthreads();
        reduce();
        __syncthreads();
        if (wave == 0) gate_store(fe, clv0, clv1, crv0, crv1);

        // ---- Rare extra chunks (>8 items/level): legacy generic path ----
        for (int base = s + 8; base < e; base += 8) {
            __syncthreads();
            if (wave == 0) prep(base, (e - base < 8) ? (e - base) : 8, lev);
            __syncthreads();
            const __hip_bfloat16* hp2 =
                (const __hip_bfloat16*)((kq < 4) ? hPl[l15 & 7] : hPr[l15 & 7]);
            float xl0 = 0.f, xl1 = 0.f, xr0 = 0.f, xr1 = 0.f;
            u32 fe2 = 1u << 29;
            if (wave == 0) {
                fe2 = (u32)outm[lane >> 3];
                const int jo = j0 + (lane & 7) * 2;
                union { u64 u; float f[2]; } t;
                t.u = *(const u64*)((const float*)cPl[lane >> 3] + jo);
                xl0 = t.f[0]; xl1 = t.f[1];
                t.u = *(const u64*)((const float*)cPr[lane >> 3] + jo);
                xr0 = t.f[0]; xr1 = t.f[1];
            }
            do_mfma(*(const v8bf*)(hp2 + kb), *(const v8bf*)(hp2 + kb + 32),
                    *(const v8bf*)(hp2 + kb + 64), *(const v8bf*)(hp2 + kb + 96));
            __syncthreads();
            reduce();
            __syncthreads();
            if (wave == 0) gate_store(fe2, xl0, xl1, xr0, xr1);
        }

        // ---- Arrival (stores acked first): plain store, no RMW ----
        if (wave == 0) {
            __builtin_amdgcn_s_waitcnt(0);  // drain wave-0 h/c stores (L2 or LLC ack)
            if (lev < ML && lane == 0)
                __hip_atomic_store(flagG + mem * 16, lev, __ATOMIC_RELAXED,
                                   __HIP_MEMORY_SCOPE_AGENT);
        }
        __syncthreads();
    }
}

// ---------------------------------------------------------------------------
extern "C" void kernel_launch(void* const* d_in, const int* in_sizes, int n_in,
                              void* d_out, int out_size, void* d_ws, size_t ws_size,
                              hipStream_t stream)
{
    const float* x   = (const float*)d_in[0];
    const int* trans = (const int*)d_in[1];
    const float* Wx  = (const float*)d_in[2];
    const float* bx  = (const float*)d_in[3];
    const float* Wg  = (const float*)d_in[4];
    const float* bg  = (const float*)d_in[5];
    const float* Wr  = (const float*)d_in[6];
    const float* br  = (const float*)d_in[7];
    float* out = (float*)d_out;

    char* p = (char*)d_ws;
    auto take = [&](size_t bytes) -> char* {
        char* r = p;
        p += (bytes + 255) & ~(size_t)255;
        return r;
    };
    __hip_bfloat16* leaf_h = (__hip_bfloat16*)take((size_t)Bb * Tt * Hh * 2);
    float* leaf_c          = (float*)take((size_t)Bb * Tt * Hh * 4);
    __hip_bfloat16* node_h = (__hip_bfloat16*)take((size_t)Bb * NNODE * Hh * 2);
    float* node_c          = (float*)take((size_t)Bb * NNODE * Hh * 4);
    int* node_l   = (int*)take((size_t)Bb * NNODE * 4);
    int* node_r   = (int*)take((size_t)Bb * NNODE * 4);
    int* root_src = (int*)take(Bb * 4);
    int* offs     = (int*)take((size_t)NG * 257 * 4);
    int* items    = (int*)take((size_t)NG * GBATCH * NNODE * 4);
    int* max_lv   = (int*)take(NG * 4);
    __hip_bfloat16* WtG = (__hip_bfloat16*)take((size_t)N5H * 1024 * 2);
    int* sync     = (int*)take((size_t)SYNC_INTS * 4);

    hipLaunchKernelGGL(leaf_kernel, dim3(Hh / 256, (Bb * Tt) / 16), dim3(256), 0, stream,
                       x, Wx, bx, Wg, bg, leaf_h, leaf_c);
    hipLaunchKernelGGL(wtr_kernel, dim3(N5H / 64, 1024 / 64), dim3(256), 0, stream,
                       Wr, WtG);
    hipLaunchKernelGGL(sched_kernel, dim3(1), dim3(64), 0, stream,
                       trans, node_l, node_r, root_src, offs, items, max_lv, sync);

    void* args[] = { (void*)&WtG, (void*)&br, (void*)&leaf_h, (void*)&leaf_c,
                     (void*)&node_h, (void*)&node_c, (void*)&node_l, (void*)&node_r,
                     (void*)&root_src, (void*)&offs, (void*)&items, (void*)&max_lv,
                     (void*)&out, (void*)&sync };
    hipLaunchCooperativeKernel((const void*)tree_kernel, dim3(256), dim3(512),
                               args, 0, stream);
}